// Round 3
// baseline (16887.708 us; speedup 1.0000x reference)
//
#include <hip/hip_runtime.h>
#include <hip/hip_bf16.h>
#include <math.h>
#include <string.h>

// Problem constants (GRUAttnDecoder): B=16, ENC=512, T=64, DIM=768, VOCAB=21128
#define Bdim 16
#define ENC 512
#define Tn 64
#define DIM 768
#define VOCAB 21128
#define SCALEF 0.03608439182435161f  // 1/sqrt(768)
#define NEGF   -1e30f
#define NBLK 256

__device__ __forceinline__ float wred_sum(float v) {
#pragma unroll
  for (int m = 32; m >= 1; m >>= 1) v += __shfl_xor(v, m, 64);
  return v;
}
__device__ __forceinline__ float sigmf(float x) { return 1.0f / (1.0f + __expf(-x)); }

// ---- coherent (cache-bypassing, agent-scope) access helpers ----
__device__ __forceinline__ float aload(const float* p) {
  return __hip_atomic_load((float*)p, __ATOMIC_RELAXED, __HIP_MEMORY_SCOPE_AGENT);
}
__device__ __forceinline__ void astore(float* p, float v) {
  __hip_atomic_store(p, v, __ATOMIC_RELAXED, __HIP_MEMORY_SCOPE_AGENT);
}
__device__ __forceinline__ float2 aload2(const float* p) {
  unsigned long long u =
      __hip_atomic_load((unsigned long long*)p, __ATOMIC_RELAXED, __HIP_MEMORY_SCOPE_AGENT);
  union { unsigned long long u; float2 f; } c; c.u = u; return c.f;
}

// one-shot two-level grid barrier. NO fences: all cross-block data travels the
// coherent atomic path (sc1), so ordering only needs vmcnt(0) before arrival.
// leaf[idx][x] (x = bid&7, 32 arrivals each, 64B-padded), root[idx] (8 arrivals).
__device__ __forceinline__ void gbar(int* leaf, int* root, int idx, int xg) {
  __syncthreads();
  if (threadIdx.x == 0) {
    asm volatile("s_waitcnt vmcnt(0)" ::: "memory");
    int prev = __hip_atomic_fetch_add(&leaf[(idx * 8 + xg) * 16], 1,
                                      __ATOMIC_RELAXED, __HIP_MEMORY_SCOPE_AGENT);
    if (prev == 31)
      __hip_atomic_fetch_add(&root[idx * 16], 1,
                             __ATOMIC_RELAXED, __HIP_MEMORY_SCOPE_AGENT);
    while (__hip_atomic_load(&root[idx * 16], __ATOMIC_RELAXED,
                             __HIP_MEMORY_SCOPE_AGENT) < 8)
      __builtin_amdgcn_s_sleep(2);
  }
  __syncthreads();
}

// ---------------- init ----------------
__global__ void k_zero(float* __restrict__ p, int n) {
  int i = blockIdx.x * blockDim.x + threadIdx.x;
  int stride = gridDim.x * blockDim.x;
  for (; i < n; i += stride) p[i] = 0.0f;
}

__global__ void k_h0(const float* __restrict__ init_h, float* __restrict__ h_all) {
  int i = blockIdx.x * blockDim.x + threadIdx.x;
  if (i < Bdim * DIM) h_all[i] = init_h[i % DIM];
}

// ---- precompute emb-part of gate preactivations + bias for all (t,b) ----
__global__ void __launch_bounds__(256, 2) k_pre(
    const int* __restrict__ din, const float* __restrict__ emb,
    const float* __restrict__ Wr, const float* __restrict__ br,
    const float* __restrict__ Wu, const float* __restrict__ bu,
    const float* __restrict__ Wc, const float* __restrict__ bc,
    float* __restrict__ P_ru, float* __restrict__ P_c) {
  const int nb = blockIdx.x, tbc = blockIdx.y;
  const int n = nb * 256 + threadIdx.x;
  const float* wrow;
  float bias;
  if (n < 768)       { wrow = Wr + n * 2304 + 768;          bias = br[n]; }
  else if (n < 1536) { wrow = Wu + (n - 768) * 2304 + 768;  bias = bu[n - 768]; }
  else               { wrow = Wc + (n - 1536) * 2304 + 768; bias = bc[n - 1536]; }
  int id[16];
#pragma unroll
  for (int i = 0; i < 16; ++i) {
    int row = tbc * 16 + i;                 // row = t*16 + b
    id[i] = din[(row & 15) * Tn + (row >> 4)];
  }
  float acc[16];
#pragma unroll
  for (int i = 0; i < 16; ++i) acc[i] = bias;
  for (int k = 0; k < DIM; k += 4) {
    float4 w = *(const float4*)(wrow + k);
#pragma unroll
    for (int i = 0; i < 16; ++i) {
      float4 x = *(const float4*)(emb + (size_t)id[i] * DIM + k);
      acc[i] = fmaf(w.x, x.x, fmaf(w.y, x.y, fmaf(w.z, x.z, fmaf(w.w, x.w, acc[i]))));
    }
  }
#pragma unroll
  for (int i = 0; i < 16; ++i) {
    int row = tbc * 16 + i;
    if (n < 1536) P_ru[(size_t)row * 1536 + n] = acc[i];
    else          P_c[(size_t)row * 768 + (n - 1536)] = acc[i];
  }
}

// ---- persistent sequential kernel: whole T-loop, 256 blocks x 512 threads ----
// Every phase: block handles batch b = bid>>4. sub = bid&15:
//   phase A: s-chunk (32 enc positions)   phase B: 96 r|u rows   phase C: 48 c rows
// bid&7 spreads same-batch blocks across XCDs; same-rows blocks share an XCD's L2.
__global__ void __launch_bounds__(512, 1) k_seq(
    const float* __restrict__ ctx, const float* __restrict__ mask,
    const float* __restrict__ Wr, const float* __restrict__ Wu,
    const float* __restrict__ Wc,
    const float* __restrict__ P_ru, const float* __restrict__ P_c,
    float* __restrict__ h_all, float* __restrict__ attnacc,
    float* __restrict__ den, float* __restrict__ r_buf,
    float* __restrict__ u_buf, int* __restrict__ leaf, int* __restrict__ root) {
  const int bid = blockIdx.x;
  const int tid = threadIdx.x;
  const int lane = tid & 63;
  const int wv = tid >> 6;            // 0..7
  const int b = bid >> 4;             // this block's batch (all phases)
  const int sub = bid & 15;
  const int xg = bid & 7;

  __shared__ float h_lds[DIM];        // h_t for batch b
  __shared__ float a_lds[DIM];        // attn vector for batch b
  __shared__ float rh_lds[DIM];       // r*h for batch b
  __shared__ float u_lds[48];
  __shared__ float e_lds[32];
  __shared__ float madd_lds[32];
  __shared__ float sden;

  if (tid < 32)
    madd_lds[tid] = (1.0f - mask[b * ENC + sub * 32 + tid]) * NEGF;

  int bidx = 0;
  for (int t = 0; t < Tn; ++t) {
    const int p = t & 1;
    // ================= phase A: attention =================
    if (tid < 384) {
      float2 v = aload2(&h_all[(size_t)(t * Bdim + b) * DIM + 2 * tid]);
      h_lds[2 * tid] = v.x; h_lds[2 * tid + 1] = v.y;
    }
    __syncthreads();
    {
      float esum = 0.f;
#pragma unroll
      for (int i = 0; i < 4; ++i) {
        const int r = wv * 4 + i;
        const int s = sub * 32 + r;
        const float* crow = ctx + ((size_t)(b * ENC + s)) * DIM;
        float dot = 0.f;
#pragma unroll
        for (int j = 0; j < 12; ++j) {
          int k = lane + 64 * j;
          dot = fmaf(crow[k], h_lds[k], dot);
        }
        dot = wred_sum(dot);
        float e = __expf(fmaf(dot, SCALEF, madd_lds[r]));  // scores O(1): no max-sub
        if (lane == 0) { e_lds[r] = e; esum += e; }
      }
      if (lane == 0) atomicAdd(&den[p * Bdim + b], esum);
    }
    __syncthreads();
    // weighted partial sum of this chunk's ctx rows -> attnacc (unnormalized)
    {
      const float* cb = ctx + ((size_t)(b * ENC + sub * 32)) * DIM;
      for (int c = tid; c < DIM; c += 512) {
        float acc = 0.f;
#pragma unroll 8
        for (int r = 0; r < 32; ++r)
          acc = fmaf(e_lds[r], cb[(size_t)r * DIM + c], acc);
        atomicAdd(&attnacc[((size_t)(p * Bdim + b)) * DIM + c], acc);
      }
    }
    gbar(leaf, root, bidx++, xg);

    // ================= phase B: r,u gates (96 rows x 1 batch) =================
    if (tid == 0) sden = aload(&den[p * Bdim + b]);
    if (tid < 384) {
      float2 v = aload2(&attnacc[((size_t)(p * Bdim + b)) * DIM + 2 * tid]);
      a_lds[2 * tid] = v.x; a_lds[2 * tid + 1] = v.y;
    }
    __syncthreads();
    {
      float inv = 1.0f / sden;
      for (int j = tid; j < DIM; j += 512) a_lds[j] *= inv;
    }
    __syncthreads();
    {
      const int r0 = sub * 96 + wv * 12;
#pragma unroll
      for (int rr = 0; rr < 12; ++rr) {
        const int row = r0 + rr;  // 0..1535 : r rows then u rows
        const float* wbase = (row < 768) ? (Wr + (size_t)row * 2304)
                                         : (Wu + (size_t)(row - 768) * 2304);
        float dot = 0.f;
#pragma unroll
        for (int j = 0; j < 12; ++j) {
          int k = lane + 64 * j;
          dot = fmaf(wbase[k], a_lds[k], dot);
          dot = fmaf(wbase[1536 + k], h_lds[k], dot);
        }
        dot = wred_sum(dot);
        if (lane == 0) {
          float s = sigmf(P_ru[(size_t)(t * Bdim + b) * 1536 + row] + dot);
          if (row < 768) astore(&r_buf[b * DIM + row], s);
          else           astore(&u_buf[b * DIM + (row - 768)], s);
        }
      }
    }
    gbar(leaf, root, bidx++, xg);

    // ================= phase C: c gate + h update (48 rows x 1 batch) ========
    const int c0 = sub * 48;
    if (tid < 384) {
      float2 v = aload2(&r_buf[b * DIM + 2 * tid]);
      rh_lds[2 * tid] = v.x * h_lds[2 * tid];
      rh_lds[2 * tid + 1] = v.y * h_lds[2 * tid + 1];
    }
    if (tid >= 448 && tid < 496) u_lds[tid - 448] = aload(&u_buf[b * DIM + c0 + (tid - 448)]);
    // zero next-parity attn accumulators (consumed only after this phase's barrier)
    {
      const int pz = 1 - p;
      if (tid >= 400 && tid < 448) astore(&attnacc[(size_t)pz * Bdim * DIM + bid * 48 + (tid - 400)], 0.f);
      if (tid == 499 && bid < Bdim) astore(&den[pz * Bdim + bid], 0.f);
    }
    __syncthreads();
    {
      const int r0 = c0 + wv * 6;
#pragma unroll
      for (int rr = 0; rr < 6; ++rr) {
        const int row = r0 + rr;  // 0..767
        const float* wbase = Wc + (size_t)row * 2304;
        float dot = 0.f;
#pragma unroll
        for (int j = 0; j < 12; ++j) {
          int k = lane + 64 * j;
          dot = fmaf(wbase[k], a_lds[k], dot);
          dot = fmaf(wbase[1536 + k], rh_lds[k], dot);
        }
        dot = wred_sum(dot);
        if (lane == 0) {
          float c = tanhf(P_c[(size_t)(t * Bdim + b) * 768 + row] + dot);
          float hp = h_lds[row];
          float u = u_lds[row - c0];
          astore(&h_all[(size_t)((t + 1) * Bdim + b) * DIM + row], hp + u * (c - hp));
        }
      }
    }
    gbar(leaf, root, bidx++, xg);
  }
}

// ---- deferred: out_all & copyq for all 1024 rows ----
__global__ void __launch_bounds__(256, 2) k_out(
    const float* __restrict__ Wo, const float* __restrict__ bo,
    const float* __restrict__ Wcp, const float* __restrict__ bcp,
    const float* __restrict__ h_all, float* __restrict__ out_all,
    float* __restrict__ copyq) {
  const int nb = blockIdx.x, tbc = blockIdx.y;
  const int n = nb * 256 + threadIdx.x;  // 0..1535
  const float* wrow;
  float bias;
  if (n < 768) { wrow = Wo + (size_t)n * 768;          bias = bo[n]; }
  else         { wrow = Wcp + (size_t)(n - 768) * 768; bias = bcp[n - 768]; }
  const float* hbase = h_all + (size_t)(tbc * 16 + 16) * DIM;  // h_new = slot t+1
  float acc[16];
#pragma unroll
  for (int i = 0; i < 16; ++i) acc[i] = bias;
  for (int k = 0; k < DIM; k += 4) {
    float4 w = *(const float4*)(wrow + k);
#pragma unroll
    for (int i = 0; i < 16; ++i) {
      float4 x = *(const float4*)(hbase + i * DIM + k);
      acc[i] = fmaf(w.x, x.x, fmaf(w.y, x.y, fmaf(w.z, x.z, fmaf(w.w, x.w, acc[i]))));
    }
  }
#pragma unroll
  for (int i = 0; i < 16; ++i) {
    int row = tbc * 16 + i;
    if (n < 768) out_all[(size_t)row * 768 + n] = acc[i];
    else         copyq[(size_t)row * 768 + (n - 768)] = acc[i];
  }
}

// ---- deferred: copy softmax num/den per (t,b) ----
__global__ void __launch_bounds__(512, 2) k_copy(
    const int* __restrict__ ids, const int* __restrict__ dtg,
    const float* __restrict__ ctx, const float* __restrict__ mask,
    const float* __restrict__ copyq,
    float* __restrict__ cnum, float* __restrict__ cden) {
  const int sc = blockIdx.x, b = blockIdx.y;
  const int lane = threadIdx.x & 63;
  const int seg = __builtin_amdgcn_readfirstlane(threadIdx.x >> 6);
  const int s = sc * 64 + lane;
  __shared__ float part[8][64];
  float creg[96];
  const float* crow = ctx + ((size_t)(b * ENC + s)) * DIM + seg * 96;
#pragma unroll
  for (int kk = 0; kk < 96; kk += 4) {
    float4 v = *(const float4*)(crow + kk);
    creg[kk] = v.x; creg[kk + 1] = v.y; creg[kk + 2] = v.z; creg[kk + 3] = v.w;
  }
  const float madd = (1.0f - mask[b * ENC + s]) * NEGF;
  const int myid = ids[b * ENC + s];
  for (int t = 0; t < Tn; ++t) {
    const int row = t * Bdim + b;
    const float* q = copyq + (size_t)row * 768 + seg * 96;
    float dot = 0.f;
#pragma unroll
    for (int kk = 0; kk < 96; kk += 4) {
      float4 qv = *(const float4*)(q + kk);
      dot = fmaf(qv.x, creg[kk], fmaf(qv.y, creg[kk + 1],
            fmaf(qv.z, creg[kk + 2], fmaf(qv.w, creg[kk + 3], dot))));
    }
    part[seg][lane] = dot;
    __syncthreads();
    if (threadIdx.x < 64) {
      float logit = madd;
#pragma unroll
      for (int w = 0; w < 8; ++w) logit += part[w][lane];
      float e = __expf(logit);
      int tgt = dtg[b * Tn + t];
      float ne = (myid == tgt) ? e : 0.f;
      float dsum = wred_sum(e);
      float nsum = wred_sum(ne);
      if (lane == 0) {
        atomicAdd(&cden[row], dsum);
        if (nsum != 0.f) atomicAdd(&cnum[row], nsum);
      }
    }
    __syncthreads();
  }
}

// ---- deferred: vocab exp-sum per row. grid (83, 32) x 256, 32 rows/block ----
__global__ void __launch_bounds__(256, 1) k_vocab(
    const float* __restrict__ emb, const float* __restrict__ out_all,
    float* __restrict__ S) {
  const int vc = blockIdx.x, tbc = blockIdx.y;
  const int tb0 = tbc * 32;
  const int v = vc * 256 + threadIdx.x;
  const bool valid = v < VOCAB;
  const int vv = valid ? v : 0;
  float acc[32];
#pragma unroll
  for (int i = 0; i < 32; ++i) acc[i] = 0.f;
  const float* erow = emb + (size_t)vv * DIM;
  for (int k = 0; k < DIM; k += 4) {
    float4 w = *(const float4*)(erow + k);
#pragma unroll
    for (int i = 0; i < 32; ++i) {
      float4 a = *(const float4*)(out_all + (size_t)(tb0 + i) * DIM + k);  // uniform
      acc[i] = fmaf(w.x, a.x, fmaf(w.y, a.y, fmaf(w.z, a.z, fmaf(w.w, a.w, acc[i]))));
    }
  }
  __shared__ float rowsum[32];
  if (threadIdx.x < 32) rowsum[threadIdx.x] = 0.f;
  __syncthreads();
  const int lane = threadIdx.x & 63;
#pragma unroll
  for (int i = 0; i < 32; ++i) {
    float e = valid ? __expf(acc[i]) : 0.f;
    float r = wred_sum(e);
    if (lane == 0) atomicAdd(&rowsum[i], r);
  }
  __syncthreads();
  if (threadIdx.x < 32) atomicAdd(&S[tb0 + threadIdx.x], rowsum[threadIdx.x]);
}

// ---- deferred: per-row target prob + loss accumulation ----
__global__ void k_tgt(
    const int* __restrict__ dtg, const float* __restrict__ out_all,
    const float* __restrict__ emb, const float* __restrict__ Wm,
    const float* __restrict__ bm, const float* __restrict__ h_all,
    const float* __restrict__ S, const float* __restrict__ cnum,
    const float* __restrict__ cden, float* __restrict__ loss) {
  const int lane = threadIdx.x & 63;
  const int w = __builtin_amdgcn_readfirstlane(threadIdx.x >> 6);
  for (int rr = 0; rr < 16; ++rr) {
    const int row = (blockIdx.x * 4 + w) * 16 + rr;
    const int t = row >> 4, b = row & 15;
    const int tgt = dtg[b * Tn + t];
    const float* orow = out_all + (size_t)row * DIM + lane * 12;
    const float* erow = emb + (size_t)tgt * DIM + lane * 12;
    const float* hrow = h_all + (size_t)(row + 16) * DIM + lane * 12;
    const float* wm = Wm + lane * 12;
    float lt = 0.f, md = 0.f;
#pragma unroll
    for (int k = 0; k < 12; k += 4) {
      float4 o = *(const float4*)(orow + k);
      float4 e = *(const float4*)(erow + k);
      float4 h = *(const float4*)(hrow + k);
      float4 m = *(const float4*)(wm + k);
      lt = fmaf(o.x, e.x, fmaf(o.y, e.y, fmaf(o.z, e.z, fmaf(o.w, e.w, lt))));
      md = fmaf(m.x, h.x, fmaf(m.y, h.y, fmaf(m.z, h.z, fmaf(m.w, h.w, md))));
    }
    lt = wred_sum(lt);
    md = wred_sum(md);
    if (lane == 0 && tgt != 0) {
      float mode = sigmf(md + bm[0]);
      float pv = __expf(lt) / S[row] * mode;
      float den = cden[row];
      float pc = (den > 0.f) ? (cnum[row] / den) : 0.f;
      float p = pv + (1.0f - mode) * pc;
      atomicAdd(&loss[0], -logf(p + 1e-6f));
      atomicAdd(&loss[1], 1.0f);
    }
  }
}

__global__ void k_write(const float* __restrict__ loss, float* __restrict__ out) {
  if (threadIdx.x < Bdim) out[threadIdx.x] = loss[0] / loss[1];
}

extern "C" void kernel_launch(void* const* d_in, const int* in_sizes, int n_in,
                              void* d_out, int out_size, void* d_ws, size_t ws_size,
                              hipStream_t stream) {
  (void)in_sizes; (void)n_in; (void)out_size; (void)ws_size;
  const int*   input_ids = (const int*)d_in[0];
  const float* ctx       = (const float*)d_in[1];
  const float* cmask     = (const float*)d_in[2];
  const int*   din       = (const int*)d_in[3];
  const int*   dtg       = (const int*)d_in[4];
  const float* embW      = (const float*)d_in[7];
  const float* Wr = (const float*)d_in[8];  const float* br  = (const float*)d_in[9];
  const float* Wu = (const float*)d_in[10]; const float* bu  = (const float*)d_in[11];
  const float* Wc = (const float*)d_in[12]; const float* bc  = (const float*)d_in[13];
  const float* Wo = (const float*)d_in[14]; const float* bo  = (const float*)d_in[15];
  const float* Wcp= (const float*)d_in[16]; const float* bcp = (const float*)d_in[17];
  const float* Wm = (const float*)d_in[18]; const float* bm  = (const float*)d_in[19];
  const float* ih = (const float*)d_in[20];

  float* ws      = (float*)d_ws;
  float* P_ru    = ws;                          // 1024*1536
  float* P_c     = P_ru + 1024 * 1536;          // 1024*768
  float* h_all   = P_c + 1024 * 768;            // 65*16*768
  float* out_all = h_all + 65 * 16 * 768;       // 1024*768
  float* copyq   = out_all + 1024 * 768;        // 1024*768
  float* r_buf   = copyq + 1024 * 768;          // 16*768
  float* u_buf   = r_buf + 16 * 768;            // 16*768
  // ---- zero region start ----
  float* S       = u_buf + 16 * 768;            // 1024
  float* cnum    = S + 1024;                    // 1024
  float* cden    = cnum + 1024;                 // 1024
  float* loss    = cden + 1024;                 // 2
  float* attnacc = loss + 2;                    // 2*16*768
  float* den     = attnacc + 2 * 16 * 768;      // 2*16
  int*   leaf    = (int*)(den + 2 * 16);        // 192*8*16 ints (64B-padded)
  int*   root    = leaf + 192 * 8 * 16;         // 192*16 ints
  const int nzero = 1024 * 3 + 2 + 2 * 16 * 768 + 32 + 192 * 8 * 16 + 192 * 16;  // 55330

  k_zero<<<16, 1024, 0, stream>>>(S, nzero);
  k_h0<<<12, 1024, 0, stream>>>(ih, h_all);
  k_pre<<<dim3(9, 64), 256, 0, stream>>>(din, embW, Wr, br, Wu, bu, Wc, bc, P_ru, P_c);

  k_seq<<<NBLK, 512, 0, stream>>>(ctx, cmask, Wr, Wu, Wc, P_ru, P_c,
                                  h_all, attnacc, den, r_buf, u_buf, leaf, root);

  k_out<<<dim3(6, 64), 256, 0, stream>>>(Wo, bo, Wcp, bcp, h_all, out_all, copyq);
  k_copy<<<dim3(8, 16), 512, 0, stream>>>(input_ids, dtg, ctx, cmask, copyq, cnum, cden);
  k_vocab<<<dim3(83, 32), 256, 0, stream>>>(embW, out_all, S);
  k_tgt<<<16, 256, 0, stream>>>(dtg, out_all, embW, Wm, bm, h_all, S, cnum, cden, loss);
  k_write<<<1, 64, 0, stream>>>(loss, (float*)d_out);
}

// Round 4
// 6880.347 us; speedup vs baseline: 2.4545x; 2.4545x over previous
//
#include <hip/hip_runtime.h>
#include <hip/hip_bf16.h>
#include <math.h>

// Problem constants (GRUAttnDecoder): B=16, ENC=512, T=64, DIM=768, VOCAB=21128
#define Bdim 16
#define ENC 512
#define Tn 64
#define DIM 768
#define VOCAB 21128
#define SCALEF 0.03608439182435161f  // 1/sqrt(768)
#define NEGF   -1e30f
#define NBLK 256
#define RU_PER 6   // r|u rows per block (1536/256)
#define C_PER 3    // c rows per block  (768/256)
#define DYN_LDS (96 * 1024)  // forces 1 block/CU -> exactly 32 blocks per XCD

__device__ __forceinline__ float wred_sum(float v) {
#pragma unroll
  for (int m = 32; m >= 1; m >>= 1) v += __shfl_xor(v, m, 64);
  return v;
}
__device__ __forceinline__ float sigmf(float x) { return 1.0f / (1.0f + __expf(-x)); }

// coherent (IF-level, L2-bypassing) access helpers
__device__ __forceinline__ void astore(float* p, float v) {
  __hip_atomic_store(p, v, __ATOMIC_RELAXED, __HIP_MEMORY_SCOPE_AGENT);
}

// one-shot two-level grid barrier, fence-free (all cross-block data is coherent).
// leaf group = PHYSICAL xcd. Trigger on every 32nd arrival so any distribution
// of blocks over leaves still reaches root==8 (no deadlock if getreg is off).
__device__ __forceinline__ void gbar(int* leaf, int* root, int idx, int xcd) {
  __syncthreads();
  if (threadIdx.x == 0) {
    asm volatile("s_waitcnt vmcnt(0)" ::: "memory");
    int prev = __hip_atomic_fetch_add(&leaf[(idx * 8 + xcd) * 16], 1,
                                      __ATOMIC_RELAXED, __HIP_MEMORY_SCOPE_AGENT);
    if (((prev + 1) & 31) == 0)
      __hip_atomic_fetch_add(&root[idx * 16], 1,
                             __ATOMIC_RELAXED, __HIP_MEMORY_SCOPE_AGENT);
    while (__hip_atomic_load(&root[idx * 16], __ATOMIC_RELAXED,
                             __HIP_MEMORY_SCOPE_AGENT) < 8)
      __builtin_amdgcn_s_sleep(1);
  }
  __syncthreads();
}

// bf16 pack helpers (manual RNE)
__device__ __forceinline__ unsigned int f2bf(float f) {
  unsigned int u = __float_as_uint(f);
  u += 0x7fffu + ((u >> 16) & 1u);
  return u >> 16;
}
__device__ __forceinline__ float bflo(unsigned int p) { return __uint_as_float(p << 16); }
__device__ __forceinline__ float bfhi(unsigned int p) { return __uint_as_float(p & 0xffff0000u); }

// ---------------- init ----------------
__global__ void k_zero_coh(unsigned long long* __restrict__ p, int n64) {
  int i = blockIdx.x * blockDim.x + threadIdx.x;
  int st = gridDim.x * blockDim.x;
  for (; i < n64; i += st)
    __hip_atomic_store(&p[i], 0ULL, __ATOMIC_RELAXED, __HIP_MEMORY_SCOPE_AGENT);
}

__global__ void k_h0(const float* __restrict__ init_h, float* __restrict__ h_all) {
  int i = blockIdx.x * blockDim.x + threadIdx.x;
  if (i < Bdim * DIM) h_all[i] = init_h[i % DIM];
}

// ---- precompute emb-part of gate preactivations + bias for all (t,b) ----
__global__ void __launch_bounds__(256, 2) k_pre(
    const int* __restrict__ din, const float* __restrict__ emb,
    const float* __restrict__ Wr, const float* __restrict__ br,
    const float* __restrict__ Wu, const float* __restrict__ bu,
    const float* __restrict__ Wc, const float* __restrict__ bc,
    float* __restrict__ P_ru, float* __restrict__ P_c) {
  const int nb = blockIdx.x, tbc = blockIdx.y;
  const int n = nb * 256 + threadIdx.x;
  const float* wrow;
  float bias;
  if (n < 768)       { wrow = Wr + n * 2304 + 768;          bias = br[n]; }
  else if (n < 1536) { wrow = Wu + (n - 768) * 2304 + 768;  bias = bu[n - 768]; }
  else               { wrow = Wc + (n - 1536) * 2304 + 768; bias = bc[n - 1536]; }
  int id[16];
#pragma unroll
  for (int i = 0; i < 16; ++i) {
    int row = tbc * 16 + i;  // row = t*16 + b
    id[i] = din[(row & 15) * Tn + (row >> 4)];
  }
  float acc[16];
#pragma unroll
  for (int i = 0; i < 16; ++i) acc[i] = bias;
  for (int k = 0; k < DIM; k += 4) {
    float4 w = *(const float4*)(wrow + k);
#pragma unroll
    for (int i = 0; i < 16; ++i) {
      float4 x = *(const float4*)(emb + (size_t)id[i] * DIM + k);
      acc[i] = fmaf(w.x, x.x, fmaf(w.y, x.y, fmaf(w.z, x.z, fmaf(w.w, x.w, acc[i]))));
    }
  }
#pragma unroll
  for (int i = 0; i < 16; ++i) {
    int row = tbc * 16 + i;
    if (n < 1536) P_ru[(size_t)row * 1536 + n] = acc[i];
    else          P_c[(size_t)row * 768 + (n - 1536)] = acc[i];
  }
}

// ---- persistent sequential kernel: weights live in VGPRs for all 64 steps ----
// block identity: physical (xcd, slot<32).  attention: batch 2*xcd+(slot&1),
// chunk slot>>1 (32 enc positions) -> ctx L2-pinned per XCD by construction.
// gates: gid = xcd*32+slot owns ru rows gid*6.. and c rows gid*3.. ;
// wave w handles batches {2w, 2w+1}.
__global__ void __launch_bounds__(512, 2) k_seq(
    const float* __restrict__ ctx, const float* __restrict__ mask,
    const float* __restrict__ Wr, const float* __restrict__ Wu,
    const float* __restrict__ Wc,
    const float* __restrict__ P_ru, const float* __restrict__ P_c,
    float* __restrict__ h_all, float* __restrict__ attnacc,
    float* __restrict__ den, float* __restrict__ r_t, float* __restrict__ u_t,
    int* __restrict__ slotctr, int* __restrict__ leaf, int* __restrict__ root) {
  extern __shared__ float dynpad[];   // 96KB requested; only e_lds used
  float* e_lds = dynpad;              // [32]
  __shared__ int slot_sh;
  const int tid = threadIdx.x;
  const int lane = tid & 63;
  const int wv = tid >> 6;  // 0..7
  int xcd;
  asm volatile("s_getreg_b32 %0, hwreg(HW_REG_XCC_ID)" : "=s"(xcd));
  xcd &= 7;
  if (tid == 0)
    slot_sh = __hip_atomic_fetch_add(&slotctr[xcd * 16], 1,
                                     __ATOMIC_RELAXED, __HIP_MEMORY_SCOPE_AGENT);
  __syncthreads();
  const int slot = slot_sh;            // 0..31 (1 block/CU guaranteed by LDS)
  const int gid = xcd * 32 + slot;     // 0..255 unique
  const int bA = 2 * xcd + (slot & 1); // attention batch
  const int chunk = slot >> 1;         // 0..15 (32 positions)
  const int ru0 = gid * RU_PER;        // 0..1535
  const int c0g = gid * C_PER;         // 0..767
  const int b0 = 2 * wv;               // this wave's two batches

  // ---- stage this block's 9 W rows into per-lane VGPRs (packed bf16) ----
  // lane cols (x-layout [a(768)|h(768)]): chunk j<6: xcol = 4*lane + 256*j
  // source col: j<3 -> xcol (attn part); j>=3 -> 1536 + (xcol-768) (h part)
  unsigned int wreg[RU_PER + C_PER][12];
#pragma unroll
  for (int i = 0; i < RU_PER + C_PER; ++i) {
    int row;
    const float* src;
    if (i < RU_PER) {
      row = ru0 + i;
      src = (row < 768) ? (Wr + (size_t)row * 2304) : (Wu + (size_t)(row - 768) * 2304);
    } else {
      src = Wc + (size_t)(c0g + (i - RU_PER)) * 2304;
    }
#pragma unroll
    for (int j = 0; j < 6; ++j) {
      int xcol = 4 * lane + 256 * j;
      int scol = (j < 3) ? xcol : (1536 + xcol - 768);
      float4 v = *(const float4*)(src + scol);
      wreg[i][2 * j]     = (f2bf(v.x)) | (f2bf(v.y) << 16);
      wreg[i][2 * j + 1] = (f2bf(v.z)) | (f2bf(v.w) << 16);
    }
  }
  // attention mask-add for this wave's 4 positions
  float madd[4];
#pragma unroll
  for (int i = 0; i < 4; ++i)
    madd[i] = (1.0f - mask[bA * ENC + chunk * 32 + 4 * wv + i]) * NEGF;

  int bidx = 0;
  for (int t = 0; t < Tn; ++t) {
    // ================= phase A: attention for batch bA =================
    {
      const float* hrow = h_all + (size_t)(t * Bdim + bA) * DIM;
      float hreg[12];
#pragma unroll
      for (int j = 0; j < 12; ++j) hreg[j] = hrow[lane + 64 * j];
      float esum = 0.f;
#pragma unroll
      for (int i = 0; i < 4; ++i) {
        const int s = chunk * 32 + 4 * wv + i;
        const float* crow = ctx + ((size_t)(bA * ENC + s)) * DIM;
        float dot = 0.f;
#pragma unroll
        for (int j = 0; j < 12; ++j) dot = fmaf(crow[lane + 64 * j], hreg[j], dot);
        dot = wred_sum(dot);
        if (lane == 0) {
          float e = __expf(fmaf(dot, SCALEF, madd[i]));  // scores O(1): no max-sub
          e_lds[4 * wv + i] = e;
          esum += e;
        }
      }
      if (lane == 0) atomicAdd(&den[t * 32 + bA], esum);
      __syncthreads();
      // weighted partial sum over this chunk's 32 ctx rows
      const float* cb = ctx + ((size_t)(bA * ENC + chunk * 32)) * DIM;
      for (int c = tid; c < DIM; c += 512) {
        float acc = 0.f;
#pragma unroll 8
        for (int r = 0; r < 32; ++r) acc = fmaf(e_lds[r], cb[(size_t)r * DIM + c], acc);
        atomicAdd(&attnacc[(size_t)(t * Bdim + bA) * DIM + c], acc);
      }
    }
    gbar(leaf, root, bidx++, xcd);

    // ================= phase B: r,u gates (reg-resident W) =================
    float4 xv[2][6];
#pragma unroll
    for (int bb = 0; bb < 2; ++bb) {
      const int b = b0 + bb;
      const float invd = 1.0f / den[t * 32 + b];  // fresh line, post-barrier
      const float* ab = attnacc + (size_t)(t * Bdim + b) * DIM;
      const float* hb = h_all + (size_t)(t * Bdim + b) * DIM;
#pragma unroll
      for (int j = 0; j < 3; ++j) {
        float4 a4 = *(const float4*)(ab + 4 * lane + 256 * j);
        xv[bb][j] = make_float4(a4.x * invd, a4.y * invd, a4.z * invd, a4.w * invd);
      }
#pragma unroll
      for (int j = 0; j < 3; ++j)
        xv[bb][3 + j] = *(const float4*)(hb + 4 * lane + 256 * j);
    }
#pragma unroll
    for (int i = 0; i < RU_PER; ++i) {
      float d0 = 0.f, d1 = 0.f;
#pragma unroll
      for (int j = 0; j < 6; ++j) {
        const unsigned int p0 = wreg[i][2 * j], p1 = wreg[i][2 * j + 1];
        const float w0 = bflo(p0), w1 = bfhi(p0), w2 = bflo(p1), w3 = bfhi(p1);
        d0 = fmaf(w0, xv[0][j].x, fmaf(w1, xv[0][j].y, fmaf(w2, xv[0][j].z, fmaf(w3, xv[0][j].w, d0))));
        d1 = fmaf(w0, xv[1][j].x, fmaf(w1, xv[1][j].y, fmaf(w2, xv[1][j].z, fmaf(w3, xv[1][j].w, d1))));
      }
      d0 = wred_sum(d0);
      d1 = wred_sum(d1);
      if (lane < 2) {
        const int b = b0 + lane;
        const float dd = lane ? d1 : d0;
        const int row = ru0 + i;
        const float s = sigmf(P_ru[(size_t)(t * Bdim + b) * 1536 + row] + dd);
        if (row < 768) astore(&r_t[(size_t)(t * Bdim + b) * DIM + row], s);
        else           astore(&u_t[(size_t)(t * Bdim + b) * DIM + (row - 768)], s);
      }
    }
    gbar(leaf, root, bidx++, xcd);

    // ================= phase C: c gate + h update =================
#pragma unroll
    for (int bb = 0; bb < 2; ++bb) {
      const int b = b0 + bb;
      const float* rb = r_t + (size_t)(t * Bdim + b) * DIM;
#pragma unroll
      for (int j = 0; j < 3; ++j) {
        float4 rv = *(const float4*)(rb + 4 * lane + 256 * j);  // fresh line
        xv[bb][3 + j].x *= rv.x; xv[bb][3 + j].y *= rv.y;
        xv[bb][3 + j].z *= rv.z; xv[bb][3 + j].w *= rv.w;
      }
    }
#pragma unroll
    for (int i = 0; i < C_PER; ++i) {
      float d0 = 0.f, d1 = 0.f;
#pragma unroll
      for (int j = 0; j < 6; ++j) {
        const unsigned int p0 = wreg[RU_PER + i][2 * j], p1 = wreg[RU_PER + i][2 * j + 1];
        const float w0 = bflo(p0), w1 = bfhi(p0), w2 = bflo(p1), w3 = bfhi(p1);
        d0 = fmaf(w0, xv[0][j].x, fmaf(w1, xv[0][j].y, fmaf(w2, xv[0][j].z, fmaf(w3, xv[0][j].w, d0))));
        d1 = fmaf(w0, xv[1][j].x, fmaf(w1, xv[1][j].y, fmaf(w2, xv[1][j].z, fmaf(w3, xv[1][j].w, d1))));
      }
      d0 = wred_sum(d0);
      d1 = wred_sum(d1);
      if (lane < 2) {
        const int b = b0 + lane;
        const float dd = lane ? d1 : d0;
        const int row = c0g + i;
        const float c = tanhf(P_c[(size_t)(t * Bdim + b) * 768 + row] + dd);
        const float hp = h_all[(size_t)(t * Bdim + b) * DIM + row];  // L2-warm
        const float u = u_t[(size_t)(t * Bdim + b) * DIM + row];     // fresh line
        astore(&h_all[(size_t)((t + 1) * Bdim + b) * DIM + row], hp + u * (c - hp));
      }
    }
    gbar(leaf, root, bidx++, xcd);
  }
}

// ---- deferred: out_all & copyq for all 1024 rows ----
__global__ void __launch_bounds__(256, 2) k_out(
    const float* __restrict__ Wo, const float* __restrict__ bo,
    const float* __restrict__ Wcp, const float* __restrict__ bcp,
    const float* __restrict__ h_all, float* __restrict__ out_all,
    float* __restrict__ copyq) {
  const int nb = blockIdx.x, tbc = blockIdx.y;
  const int n = nb * 256 + threadIdx.x;  // 0..1535
  const float* wrow;
  float bias;
  if (n < 768) { wrow = Wo + (size_t)n * 768;          bias = bo[n]; }
  else         { wrow = Wcp + (size_t)(n - 768) * 768; bias = bcp[n - 768]; }
  const float* hbase = h_all + (size_t)(tbc * 16 + 16) * DIM;  // h_new = slot t+1
  float acc[16];
#pragma unroll
  for (int i = 0; i < 16; ++i) acc[i] = bias;
  for (int k = 0; k < DIM; k += 4) {
    float4 w = *(const float4*)(wrow + k);
#pragma unroll
    for (int i = 0; i < 16; ++i) {
      float4 x = *(const float4*)(hbase + i * DIM + k);
      acc[i] = fmaf(w.x, x.x, fmaf(w.y, x.y, fmaf(w.z, x.z, fmaf(w.w, x.w, acc[i]))));
    }
  }
#pragma unroll
  for (int i = 0; i < 16; ++i) {
    int row = tbc * 16 + i;
    if (n < 768) out_all[(size_t)row * 768 + n] = acc[i];
    else         copyq[(size_t)row * 768 + (n - 768)] = acc[i];
  }
}

// ---- deferred: copy softmax num/den per (t,b) ----
__global__ void __launch_bounds__(512, 2) k_copy(
    const int* __restrict__ ids, const int* __restrict__ dtg,
    const float* __restrict__ ctx, const float* __restrict__ mask,
    const float* __restrict__ copyq,
    float* __restrict__ cnum, float* __restrict__ cden) {
  const int sc = blockIdx.x, b = blockIdx.y;
  const int lane = threadIdx.x & 63;
  const int seg = __builtin_amdgcn_readfirstlane(threadIdx.x >> 6);
  const int s = sc * 64 + lane;
  __shared__ float part[8][64];
  float creg[96];
  const float* crow = ctx + ((size_t)(b * ENC + s)) * DIM + seg * 96;
#pragma unroll
  for (int kk = 0; kk < 96; kk += 4) {
    float4 v = *(const float4*)(crow + kk);
    creg[kk] = v.x; creg[kk + 1] = v.y; creg[kk + 2] = v.z; creg[kk + 3] = v.w;
  }
  const float madd = (1.0f - mask[b * ENC + s]) * NEGF;
  const int myid = ids[b * ENC + s];
  for (int t = 0; t < Tn; ++t) {
    const int row = t * Bdim + b;
    const float* q = copyq + (size_t)row * 768 + seg * 96;
    float dot = 0.f;
#pragma unroll
    for (int kk = 0; kk < 96; kk += 4) {
      float4 qv = *(const float4*)(q + kk);
      dot = fmaf(qv.x, creg[kk], fmaf(qv.y, creg[kk + 1],
            fmaf(qv.z, creg[kk + 2], fmaf(qv.w, creg[kk + 3], dot))));
    }
    part[seg][lane] = dot;
    __syncthreads();
    if (threadIdx.x < 64) {
      float logit = madd;
#pragma unroll
      for (int w = 0; w < 8; ++w) logit += part[w][lane];
      float e = __expf(logit);
      int tgt = dtg[b * Tn + t];
      float ne = (myid == tgt) ? e : 0.f;
      float dsum = wred_sum(e);
      float nsum = wred_sum(ne);
      if (lane == 0) {
        atomicAdd(&cden[row], dsum);
        if (nsum != 0.f) atomicAdd(&cnum[row], nsum);
      }
    }
    __syncthreads();
  }
}

// ---- deferred: vocab exp-sum per row. grid (83, 32) x 256, 32 rows/block ----
__global__ void __launch_bounds__(256, 1) k_vocab(
    const float* __restrict__ emb, const float* __restrict__ out_all,
    float* __restrict__ S) {
  const int vc = blockIdx.x, tbc = blockIdx.y;
  const int tb0 = tbc * 32;
  const int v = vc * 256 + threadIdx.x;
  const bool valid = v < VOCAB;
  const int vv = valid ? v : 0;
  float acc[32];
#pragma unroll
  for (int i = 0; i < 32; ++i) acc[i] = 0.f;
  const float* erow = emb + (size_t)vv * DIM;
  for (int k = 0; k < DIM; k += 4) {
    float4 w = *(const float4*)(erow + k);
#pragma unroll
    for (int i = 0; i < 32; ++i) {
      float4 a = *(const float4*)(out_all + (size_t)(tb0 + i) * DIM + k);
      acc[i] = fmaf(w.x, a.x, fmaf(w.y, a.y, fmaf(w.z, a.z, fmaf(w.w, a.w, acc[i]))));
    }
  }
  __shared__ float rowsum[32];
  if (threadIdx.x < 32) rowsum[threadIdx.x] = 0.f;
  __syncthreads();
  const int lane = threadIdx.x & 63;
#pragma unroll
  for (int i = 0; i < 32; ++i) {
    float e = valid ? __expf(acc[i]) : 0.f;
    float r = wred_sum(e);
    if (lane == 0) atomicAdd(&rowsum[i], r);
  }
  __syncthreads();
  if (threadIdx.x < 32) atomicAdd(&S[tb0 + threadIdx.x], rowsum[threadIdx.x]);
}

// ---- deferred: per-row target prob + loss accumulation ----
__global__ void k_tgt(
    const int* __restrict__ dtg, const float* __restrict__ out_all,
    const float* __restrict__ emb, const float* __restrict__ Wm,
    const float* __restrict__ bm, const float* __restrict__ h_all,
    const float* __restrict__ S, const float* __restrict__ cnum,
    const float* __restrict__ cden, float* __restrict__ loss) {
  const int lane = threadIdx.x & 63;
  const int w = __builtin_amdgcn_readfirstlane(threadIdx.x >> 6);
  for (int rr = 0; rr < 16; ++rr) {
    const int row = (blockIdx.x * 4 + w) * 16 + rr;
    const int t = row >> 4, b = row & 15;
    const int tgt = dtg[b * Tn + t];
    const float* orow = out_all + (size_t)row * DIM + lane * 12;
    const float* erow = emb + (size_t)tgt * DIM + lane * 12;
    const float* hrow = h_all + (size_t)(row + 16) * DIM + lane * 12;
    const float* wm = Wm + lane * 12;
    float lt = 0.f, md = 0.f;
#pragma unroll
    for (int k = 0; k < 12; k += 4) {
      float4 o = *(const float4*)(orow + k);
      float4 e = *(const float4*)(erow + k);
      float4 h = *(const float4*)(hrow + k);
      float4 m = *(const float4*)(wm + k);
      lt = fmaf(o.x, e.x, fmaf(o.y, e.y, fmaf(o.z, e.z, fmaf(o.w, e.w, lt))));
      md = fmaf(m.x, h.x, fmaf(m.y, h.y, fmaf(m.z, h.z, fmaf(m.w, h.w, md))));
    }
    lt = wred_sum(lt);
    md = wred_sum(md);
    if (lane == 0 && tgt != 0) {
      float mode = sigmf(md + bm[0]);
      float pv = __expf(lt) / S[row] * mode;
      float den = cden[row];
      float pc = (den > 0.f) ? (cnum[row] / den) : 0.f;
      float p = pv + (1.0f - mode) * pc;
      atomicAdd(&loss[0], -logf(p + 1e-6f));
      atomicAdd(&loss[1], 1.0f);
    }
  }
}

__global__ void k_write(const float* __restrict__ loss, float* __restrict__ out) {
  if (threadIdx.x < Bdim) out[threadIdx.x] = loss[0] / loss[1];
}

extern "C" void kernel_launch(void* const* d_in, const int* in_sizes, int n_in,
                              void* d_out, int out_size, void* d_ws, size_t ws_size,
                              hipStream_t stream) {
  (void)in_sizes; (void)n_in; (void)out_size; (void)ws_size;
  const int*   input_ids = (const int*)d_in[0];
  const float* ctx       = (const float*)d_in[1];
  const float* cmask     = (const float*)d_in[2];
  const int*   din       = (const int*)d_in[3];
  const int*   dtg       = (const int*)d_in[4];
  const float* embW      = (const float*)d_in[7];
  const float* Wr = (const float*)d_in[8];  const float* br  = (const float*)d_in[9];
  const float* Wu = (const float*)d_in[10]; const float* bu  = (const float*)d_in[11];
  const float* Wc = (const float*)d_in[12]; const float* bc  = (const float*)d_in[13];
  const float* Wo = (const float*)d_in[14]; const float* bo  = (const float*)d_in[15];
  const float* Wcp= (const float*)d_in[16]; const float* bcp = (const float*)d_in[17];
  const float* Wm = (const float*)d_in[18]; const float* bm  = (const float*)d_in[19];
  const float* ih = (const float*)d_in[20];

  float* ws      = (float*)d_ws;
  float* P_ru    = ws;                          // 1024*1536
  float* P_c     = P_ru + 1024 * 1536;          // 1024*768
  float* h_all   = P_c + 1024 * 768;            // 65*16*768
  float* out_all = h_all + 65 * 16 * 768;       // 1024*768
  float* copyq   = out_all + 1024 * 768;        // 1024*768
  float* r_t     = copyq + 1024 * 768;          // 64*16*768 (per-t, fresh lines)
  float* u_t     = r_t + 64 * 16 * 768;         // 64*16*768
  // ---- coherently-zeroed region (no cached zero lines anywhere) ----
  float* S       = u_t + 64 * 16 * 768;         // 1024
  float* cnum    = S + 1024;                    // 1024
  float* cden    = cnum + 1024;                 // 1024
  float* loss    = cden + 1024;                 // 2 (+30 pad -> 128B alignment)
  float* attnacc = loss + 32;                   // 64*16*768
  float* den     = attnacc + 64 * 16 * 768;     // 64*32 (128B per t slot)
  int*   slotctr = (int*)(den + 64 * 32);       // 8*16
  int*   leaf    = slotctr + 128;               // 192*8*16
  int*   root    = leaf + 192 * 8 * 16;         // 192*16
  const int nzero64 = (3 * 1024 + 32 + 64 * 16 * 768 + 64 * 32 + 128 +
                       192 * 8 * 16 + 192 * 16) / 2;  // 409,680 u64

  hipFuncSetAttribute((const void*)k_seq,
                      hipFuncAttributeMaxDynamicSharedMemorySize, DYN_LDS);

  k_zero_coh<<<256, 1024, 0, stream>>>((unsigned long long*)S, nzero64);
  k_h0<<<12, 1024, 0, stream>>>(ih, h_all);
  k_pre<<<dim3(9, 64), 256, 0, stream>>>(din, embW, Wr, br, Wu, bu, Wc, bc, P_ru, P_c);

  k_seq<<<NBLK, 512, DYN_LDS, stream>>>(ctx, cmask, Wr, Wu, Wc, P_ru, P_c,
                                        h_all, attnacc, den, r_t, u_t,
                                        slotctr, leaf, root);

  k_out<<<dim3(6, 64), 256, 0, stream>>>(Wo, bo, Wcp, bcp, h_all, out_all, copyq);
  k_copy<<<dim3(8, 16), 512, 0, stream>>>(input_ids, dtg, ctx, cmask, copyq, cnum, cden);
  k_vocab<<<dim3(83, 32), 256, 0, stream>>>(embW, out_all, S);
  k_tgt<<<16, 256, 0, stream>>>(dtg, out_all, embW, Wm, bm, h_all, S, cnum, cden, loss);
  k_write<<<1, 64, 0, stream>>>(loss, (float*)d_out);
}